// Round 15
// baseline (230.797 us; speedup 1.0000x reference)
//
#include <hip/hip_runtime.h>
#include <hip/hip_bf16.h>

typedef unsigned short u16;
typedef unsigned int   u32;
typedef __bf16 bf16x8 __attribute__((ext_vector_type(8)));
typedef float  f32x4  __attribute__((ext_vector_type(4)));

#define BB 2
#define TT 8192
#define DD 512
#define HH 8
#define WW 256
#define DH 64
#define NX 8388608   // 16384*512
#define NW 262144    // 512*512

__device__ __forceinline__ float b2f(u16 u) {
    unsigned int x = ((unsigned int)u) << 16;
    return __builtin_bit_cast(float, x);
}
__device__ __forceinline__ u16 f2b(float f) {
    __bf16 h = (__bf16)f;
    return __builtin_bit_cast(u16, h);
}
__device__ __forceinline__ bf16x8 ldsfrag(const u16* p) {
    return *(const bf16x8*)p;
}
__device__ __forceinline__ f32x4 mfma16(bf16x8 a, bf16x8 b, f32x4 c) {
    return __builtin_amdgcn_mfma_f32_16x16x32_bf16(a, b, c, 0, 0, 0);
}

typedef __attribute__((address_space(1))) u32 gu32;
typedef __attribute__((address_space(3))) u32 lu32;
// async global->LDS, 16B per lane, dest = wave-uniform base + lane*16
__device__ __forceinline__ void gl_lds(const u16* g, u16* l) {
    __builtin_amdgcn_global_load_lds((gu32*)g, (lu32*)l, 16, 0, 0);
}

// ---- convert all 9 inputs to bf16 in workspace (vectorized, 8 elem/thread).
__device__ __forceinline__ void cvt8(const void* s, u16* d, long i, int f) {
    if (f) {
        const u32* sp = (const u32*)s + i;
        uint4 a = *(const uint4*)(sp);
        uint4 b = *(const uint4*)(sp + 4);
        u16 o[8];
        o[0] = f2b(__builtin_bit_cast(float, a.x));
        o[1] = f2b(__builtin_bit_cast(float, a.y));
        o[2] = f2b(__builtin_bit_cast(float, a.z));
        o[3] = f2b(__builtin_bit_cast(float, a.w));
        o[4] = f2b(__builtin_bit_cast(float, b.x));
        o[5] = f2b(__builtin_bit_cast(float, b.y));
        o[6] = f2b(__builtin_bit_cast(float, b.z));
        o[7] = f2b(__builtin_bit_cast(float, b.w));
        *(uint4*)(d + i) = *(const uint4*)o;
    } else {
        *(uint4*)(d + i) = *(const uint4*)((const u16*)s + i);
    }
}

__global__ void convert_all(const void* x, const void* Wq, const void* bq,
                            const void* Wk, const void* bk, const void* Wv,
                            const void* bv, const void* Wo, const void* bo,
                            u16* __restrict__ xb, u16* __restrict__ Wcat,
                            u16* __restrict__ Wob, u16* __restrict__ bcat,
                            u16* __restrict__ bob, int* __restrict__ flagw)
{
    __shared__ int sflag;
    const int tid = threadIdx.x;
    if (tid == 0) sflag = 0;
    __syncthreads();
    int mybad = 0;
    for (int i = tid; i < 2048; i += 256) {
        float v = b2f(((const u16*)x)[i]);
        if (!(fabsf(v) < 100.f)) mybad = 1;   // fp32 mantissa halves look wild
    }
    if (mybad) atomicOr(&sflag, 1);
    __syncthreads();
    const int f = sflag ? 1 : 0;
    if (blockIdx.x == 0 && tid == 0) *flagw = f;

    long i = ((long)blockIdx.x * 256 + tid) * 8;
    if (i < NX)            { cvt8(x,  xb,           i, f); return; }
    i -= NX;
    if (i < NW)            { cvt8(Wq, Wcat,         i, f); return; }
    i -= NW;
    if (i < NW)            { cvt8(Wk, Wcat + NW,    i, f); return; }
    i -= NW;
    if (i < NW)            { cvt8(Wv, Wcat + 2*NW,  i, f); return; }
    i -= NW;
    if (i < NW)            { cvt8(Wo, Wob,          i, f); return; }
    i -= NW;
    if (i < 512)           { cvt8(bq, bcat,         i, f); return; }
    i -= 512;
    if (i < 512)           { cvt8(bk, bcat + 512,   i, f); return; }
    i -= 512;
    if (i < 512)           { cvt8(bv, bcat + 1024,  i, f); return; }
    i -= 512;
    if (i < 512)           { cvt8(bo, bob,          i, f); }
}

// 256x256-tile GEMM, K=512. Round-15: r12 geometry + SPILL FIX.
// r12 post-mortem: VGPR_Count was pinned at exactly 128 (= acc[8][4] alone)
// with +65MB scratch WRITE - the allocator targeted 4 waves/EU under
// __launch_bounds__(512,2) heuristics and spilled the accumulator, even
// though the live set (acc 128 + 24 frags 96 + addr ~20 = ~245) fits the
// 256-VGPR cap that bound permits. Single-variable change from r12:
// __launch_bounds__(512,1) lifts the allocator target to 1 wave/EU
// (cap 512) -> no spill. Tests the LDS-intensity model cleanly:
// wave-output 128x64 -> 375B ds_read per MFMA (vs 500B at 64x64/wave),
// per-CU-round LDS time 9.2k vs 12.3k cycles.
// Schedule (r12): 2-buffer ping-pong, stage(t+1) -> 24 ds_read_b128 ->
// lgkm(0) -> setprio(1) -> 64 MFMA -> vmcnt(0) -> barrier. 128KB LDS,
// 1 blk/CU. Same staging XOR-swizzle (0 conflicts measured).
// out[m,n] = sum_k A[m,k]*Bw[n,k] + bias[n].
// mode 0 (fused QKV, N=1536): seg0->out0 (Q), seg1->out1 (K), seg2->out2
//   (V TRANSPOSED [(b*8+h)*64+d][t]).  mode 1 (O-proj): out0, fp32 if *flagp.
__global__ __launch_bounds__(512, 1)
void gemm256(const u16* __restrict__ A, const u16* __restrict__ Bw,
             const u16* __restrict__ bias, void* __restrict__ out0,
             u16* __restrict__ out1, u16* __restrict__ out2,
             int mode, const int* __restrict__ flagp)
{
    __shared__ __align__(16) u16 AsF[2][256 * 64];   // 64 KB
    __shared__ __align__(16) u16 BsF[2][256 * 64];   // 64 KB (128 KB, 1 blk/CU)

    const int tid  = threadIdx.x;
    const int lane = tid & 63;
    const int wv   = tid >> 6;          // 0..7
    const int col  = lane & 15;
    const int quad = lane >> 4;
    const int wm   = (wv & 1) * 128;    // 0,128
    const int wn   = (wv >> 1) * 64;    // 0,64,128,192
    const int m0   = blockIdx.x * 256;
    const int n0   = blockIdx.y * 256;

    f32x4 acc[8][4] = {};

    // staging: lane l covers row-in-group lr=l>>3, 16B slot lc=l&7;
    // source k-slot XOR-swizzled by row&7 (= lr, groups 8-row-aligned).
    const int lr  = lane >> 3;
    const int lc  = lane & 7;
    const int cbs = lc ^ lr;

    // per wave per tile: 4 A-groups + 4 B-groups = 8 gl_lds (32 groups each)
    auto STG = [&](int buf, int k0) {
        #pragma unroll
        for (int i = 0; i < 4; i++) {
            const int g = wv * 4 + i;                     // 0..31 (256 rows)
            gl_lds(A  + (size_t)(m0 + g * 8 + lr) * 512 + k0 + cbs * 8,
                   &AsF[buf][g * 512]);
            gl_lds(Bw + (size_t)(n0 + g * 8 + lr) * 512 + k0 + cbs * 8,
                   &BsF[buf][g * 512]);
        }
    };

    // prologue: tile 0 staged; drain; barrier
    STG(0, 0);
    asm volatile("s_waitcnt vmcnt(0)" ::: "memory");
    __builtin_amdgcn_s_barrier();
    __builtin_amdgcn_sched_barrier(0);

    #pragma unroll
    for (int t = 0; t < 8; t++) {                 // static after full unroll
        const int p = t & 1;
        if (t < 7) STG(p ^ 1, (t + 1) * 64);
        bf16x8 fa[2][8], fb[2][4];
        #pragma unroll
        for (int kk = 0; kk < 2; kk++) {
            #pragma unroll
            for (int mi = 0; mi < 8; mi++)
                fa[kk][mi] = ldsfrag(&AsF[p][(wm + mi * 16 + col) * 64 + ((kk * 4 + quad) ^ (col & 7)) * 8]);
            #pragma unroll
            for (int ni = 0; ni < 4; ni++)
                fb[kk][ni] = ldsfrag(&BsF[p][(wn + ni * 16 + col) * 64 + ((kk * 4 + quad) ^ (col & 7)) * 8]);
        }
        asm volatile("s_waitcnt lgkmcnt(0)" ::: "memory");
        __builtin_amdgcn_sched_barrier(0);
        __builtin_amdgcn_s_setprio(1);
        #pragma unroll
        for (int kk = 0; kk < 2; kk++)
            #pragma unroll
            for (int mi = 0; mi < 8; mi++)
                #pragma unroll
                for (int ni = 0; ni < 4; ni++)
                    acc[mi][ni] = mfma16(fa[kk][mi], fb[kk][ni], acc[mi][ni]);
        __builtin_amdgcn_s_setprio(0);
        if (t < 7) {
            // next tile's 8 loads had the whole MFMA span to land; drain rest
            asm volatile("s_waitcnt vmcnt(0)" ::: "memory");
            __builtin_amdgcn_s_barrier();
            __builtin_amdgcn_sched_barrier(0);
        }
    }

    if (mode == 0) {
        #pragma unroll
        for (int ni = 0; ni < 4; ni++) {
            const int gn = n0 + wn + ni * 16 + col;     // 0..1535
            const float bv = b2f(bias[gn]);
            const int seg = gn >> 9;
            #pragma unroll
            for (int mi = 0; mi < 8; mi++) {
                const int gmb = m0 + wm + mi * 16 + quad * 4;
                if (seg < 2) {
                    u16* dst = (seg == 0) ? (u16*)out0 : out1;
                    #pragma unroll
                    for (int r = 0; r < 4; r++)
                        dst[(size_t)(gmb + r) * 512 + (gn & 511)] = f2b(acc[mi][ni][r] + bv);
                } else {
                    const int d = gn & 63, hh = (gn >> 6) & 7;
                    const int bb = gmb >> 13, t = gmb & 8191;
                    u16 pb[4];
                    #pragma unroll
                    for (int r = 0; r < 4; r++) pb[r] = f2b(acc[mi][ni][r] + bv);
                    uint2 pk;
                    pk.x = pb[0] | ((u32)pb[1] << 16);
                    pk.y = pb[2] | ((u32)pb[3] << 16);
                    *(uint2*)&out2[((size_t)(bb * 8 + hh) * 64 + d) * 8192 + t] = pk;
                }
            }
        }
    } else {
        const int outf32 = *flagp;
        #pragma unroll
        for (int ni = 0; ni < 4; ni++) {
            const int gn = n0 + wn + ni * 16 + col;
            const float bv = b2f(bias[gn]);
            #pragma unroll
            for (int mi = 0; mi < 8; mi++) {
                #pragma unroll
                for (int r = 0; r < 4; r++) {
                    const int gm = m0 + wm + mi * 16 + quad * 4 + r;
                    const float v = acc[mi][ni][r] + bv;
                    if (outf32) ((float*)out0)[(size_t)gm * 512 + gn] = v;
                    else        ((u16*)out0)[(size_t)gm * 512 + gn]  = f2b(v);
                }
            }
        }
    }
}

// Local attention, block = (b,h,chunk): 256 queries, 8 waves x 32 queries.
// Round-10 structure kept (measured good): P in registers - Ps LDS
// round-trip eliminated via the key<->k-slot remap kappa(kt,quad,j) =
// (2kt+(j>>2))*16+quad*4+(j&3); PV's B-fragment is the lane's own QK^T
// output, V read as 2x ds_read_b64 per di with the same map. LDS 32KB.
// No max-subtraction (scores O(6), softmax shift-invariant).
__global__ __launch_bounds__(512, 4)
void attn_local(const u16* __restrict__ Qg, const u16* __restrict__ Kg,
                const u16* __restrict__ VTg, u16* __restrict__ Og)
{
    __shared__ __align__(16) u16 Ks[2][64 * 64];   // 16 KB
    __shared__ __align__(16) u16 VTs[2][64 * 64];  // 16 KB (32 KB total)

    const int tid  = threadIdx.x;
    const int lane = tid & 63;
    const int wv   = tid >> 6;          // 0..7
    const int col  = lane & 15;
    const int quad = lane >> 4;

    const int idx = blockIdx.x;
    const int c = idx & 31;
    const int h = (idx >> 5) & 7;
    const int b = idx >> 8;

    const int t0 = c * WW;
    const int wq = wv * 32;             // this wave's 32 queries

    const int sc_lo = (c == 0) ? 4 : 0;                 // kstart >= 0
    const int nsc   = (c == 0 || c == 31) ? 8 : 12;     // kstart < T

    const int ldr = lane >> 3;            // staging row-within-group (0..7)
    const int ldc = lane & 7;

    // Q fragments (B-operand): lane holds Q[t0+wq+qi*16+col][kk*32+quad*8..+8]
    bf16x8 qf[2][2];
    {
        const size_t qbase = ((size_t)(b * TT + t0 + wq + col)) * DD + h * DH + quad * 8;
        #pragma unroll
        for (int qi = 0; qi < 2; qi++)
            #pragma unroll
            for (int kk = 0; kk < 2; kk++)
                qf[qi][kk] = *(const bf16x8*)(Qg + qbase + (size_t)qi * 16 * DD + kk * 32);
    }

    f32x4 o[4][2] = {};                 // O^T accum: [di(d-tile)][qi(q-tile)]
    float lsum[2] = {0.f, 0.f};         // per-lane partial l for q=qi*16+col

    // prefetch first sub-chunk into buf 0 (one K + one VT row-group per wave)
    {
        const int kstart = t0 - WW + sc_lo * 64;
        const int rr = wv * 8 + ldr;
        const int cb = ldc ^ (rr & 7);
        gl_lds(Kg  + ((size_t)(b * TT + kstart + rr)) * DD + h * DH + cb * 8,
               &Ks[0][wv * 512]);
        gl_lds(VTg + ((size_t)((b * HH + h) * DH + rr)) * TT + kstart + cb * 8,
               &VTs[0][wv * 512]);
    }

    for (int it = 0; it < nsc; it++) {
        __syncthreads();   // drains loads for buf it&1; prev readers of other buf done
        if (it + 1 < nsc) {
            const int kstart = t0 - WW + (sc_lo + it + 1) * 64;
            const int buf = (it + 1) & 1;
            const int rr = wv * 8 + ldr;
            const int cb = ldc ^ (rr & 7);
            gl_lds(Kg  + ((size_t)(b * TT + kstart + rr)) * DD + h * DH + cb * 8,
                   &Ks[buf][wv * 512]);
            gl_lds(VTg + ((size_t)((b * HH + h) * DH + rr)) * TT + kstart + cb * 8,
                   &VTs[buf][wv * 512]);
        }
        const u16* ks = &Ks[it & 1][0];
        const u16* vs = &VTs[it & 1][0];

        #pragma unroll
        for (int half = 0; half < 2; half++) {      // half == kt
            uint2 p2[2][2];                          // [nsl][qi] packed bf16 p
            #pragma unroll
            for (int nsl = 0; nsl < 2; nsl++) {
                const int ns = half * 2 + nsl;
                const int row = ns * 16 + col;
                bf16x8 ka0 = ldsfrag(&ks[row * 64 + ((0 + quad) ^ (col & 7)) * 8]);
                bf16x8 ka1 = ldsfrag(&ks[row * 64 + ((4 + quad) ^ (col & 7)) * 8]);
                #pragma unroll
                for (int qi = 0; qi < 2; qi++) {
                    f32x4 sv = (f32x4){0.f, 0.f, 0.f, 0.f};
                    sv = mfma16(ka0, qf[qi][0], sv);
                    sv = mfma16(ka1, qf[qi][1], sv);
                    u16 pb[4];
                    #pragma unroll
                    for (int r = 0; r < 4; r++) {
                        const float p = __expf(sv[r] * 0.125f);
                        pb[r] = f2b(p);
                        lsum[qi] += p;
                    }
                    p2[nsl][qi].x = pb[0] | ((u32)pb[1] << 16);
                    p2[nsl][qi].y = pb[2] | ((u32)pb[3] << 16);
                }
            }
            // PV kt=half. B-fragment is lane-local: element j = p[2kt+(j>>2)][j&3]
            bf16x8 pf[2];
            #pragma unroll
            for (int qi = 0; qi < 2; qi++) {
                uint4 w;
                w.x = p2[0][qi].x; w.y = p2[0][qi].y;
                w.z = p2[1][qi].x; w.w = p2[1][qi].y;
                pf[qi] = __builtin_bit_cast(bf16x8, w);
            }
            // V fragment: element j = VT[d][kappa] -> two b64 chunks per di
            const int glo = (half * 4 +     (quad >> 1)) ^ (col & 7);
            const int ghi = (half * 4 + 2 + (quad >> 1)) ^ (col & 7);
            const int hb  = (quad & 1) * 8;              // byte offset in granule
            #pragma unroll
            for (int di = 0; di < 4; di++) {
                const char* rowp = (const char*)&vs[(di * 16 + col) * 64];
                uint2 lo = *(const uint2*)(rowp + glo * 16 + hb);
                uint2 hi = *(const uint2*)(rowp + ghi * 16 + hb);
                uint4 w4;
                w4.x = lo.x; w4.y = lo.y; w4.z = hi.x; w4.w = hi.y;
                bf16x8 va = __builtin_bit_cast(bf16x8, w4);
                #pragma unroll
                for (int qi = 0; qi < 2; qi++)
                    o[di][qi] = mfma16(va, pf[qi], o[di][qi]);
            }
        }
    }

    // final l reduction over quads (lanes col,col+16,col+32,col+48 share q)
    #pragma unroll
    for (int qi = 0; qi < 2; qi++) {
        float l = lsum[qi];
        l += __shfl_xor(l, 16);
        l += __shfl_xor(l, 32);
        lsum[qi] = 1.0f / l;
    }

    // store O^T: element (di,qi,r): d = di*16+quad*4+r, q = qi*16+col
    #pragma unroll
    for (int qi = 0; qi < 2; qi++) {
        const size_t ob = ((size_t)(b * TT + t0 + wq + qi * 16 + col)) * DD + h * DH + quad * 4;
        #pragma unroll
        for (int di = 0; di < 4; di++) {
            u16 pb[4];
            #pragma unroll
            for (int r = 0; r < 4; r++) pb[r] = f2b(o[di][qi][r] * lsum[qi]);
            uint2 pk;
            pk.x = pb[0] | ((u32)pb[1] << 16);
            pk.y = pb[2] | ((u32)pb[3] << 16);
            *(uint2*)&Og[ob + di * 16] = pk;
        }
    }
}

extern "C" void kernel_launch(void* const* d_in, const int* in_sizes, int n_in,
                              void* d_out, int out_size, void* d_ws, size_t ws_size,
                              hipStream_t stream)
{
    u16* ws   = (u16*)d_ws;
    u16* xb   = ws;                       // NX
    u16* Wcat = xb + NX;                  // 3*NW  (Wq,Wk,Wv rows concatenated)
    u16* Wob  = Wcat + 3 * NW;            // NW
    u16* bcat = Wob + NW;                 // 1536
    u16* bob  = bcat + 1536;              // 512
    u16* qws  = bob + 512;                // NX   Q  [b*T+t][h*64+d]
    u16* kws  = qws + NX;                 // NX   K  same
    u16* vtws = kws + NX;                 // NX   V^T [(b*8+h)*64+d][t]
    u16* aws  = vtws + NX;                // NX   attn out [b*T+t][h*64+d]
    int* flag = (int*)(aws + NX);

    // 9439232 elements / 8 per thread / 256 per block = 4609 blocks
    convert_all<<<4609, 256, 0, stream>>>(
        d_in[0], d_in[1], d_in[2], d_in[3], d_in[4], d_in[5], d_in[6], d_in[7], d_in[8],
        xb, Wcat, Wob, bcat, bob, flag);

    // fused QKV projection: N = 1536, 256x256 tiles -> 64x6 = 384 blocks
    gemm256<<<dim3(64, 6), 512, 0, stream>>>(xb, Wcat, bcat, qws, kws, vtws, 0, flag);
    // local attention: 512 blocks x 512 threads
    attn_local<<<dim3(BB * HH * 32), 512, 0, stream>>>(qws, kws, vtws, aws);
    // output projection: 64x2 = 128 blocks
    gemm256<<<dim3(64, 2), 512, 0, stream>>>(aws, Wob, bob, d_out, nullptr, nullptr, 1, flag);
}

// Round 16
// 189.430 us; speedup vs baseline: 1.2184x; 1.2184x over previous
//
#include <hip/hip_runtime.h>
#include <hip/hip_bf16.h>

typedef unsigned short u16;
typedef unsigned int   u32;
typedef __bf16 bf16x8 __attribute__((ext_vector_type(8)));
typedef float  f32x4  __attribute__((ext_vector_type(4)));

#define BB 2
#define TT 8192
#define DD 512
#define HH 8
#define WW 256
#define DH 64
#define NX 8388608   // 16384*512
#define NW 262144    // 512*512

__device__ __forceinline__ float b2f(u16 u) {
    unsigned int x = ((unsigned int)u) << 16;
    return __builtin_bit_cast(float, x);
}
__device__ __forceinline__ u16 f2b(float f) {
    __bf16 h = (__bf16)f;
    return __builtin_bit_cast(u16, h);
}
__device__ __forceinline__ bf16x8 ldsfrag(const u16* p) {
    return *(const bf16x8*)p;
}
__device__ __forceinline__ f32x4 mfma16(bf16x8 a, bf16x8 b, f32x4 c) {
    return __builtin_amdgcn_mfma_f32_16x16x32_bf16(a, b, c, 0, 0, 0);
}

typedef __attribute__((address_space(1))) u32 gu32;
typedef __attribute__((address_space(3))) u32 lu32;
// async global->LDS, 16B per lane, dest = wave-uniform base + lane*16
__device__ __forceinline__ void gl_lds(const u16* g, u16* l) {
    __builtin_amdgcn_global_load_lds((gu32*)g, (lu32*)l, 16, 0, 0);
}

// ---- convert all 9 inputs to bf16 in workspace (vectorized, 8 elem/thread).
__device__ __forceinline__ void cvt8(const void* s, u16* d, long i, int f) {
    if (f) {
        const u32* sp = (const u32*)s + i;
        uint4 a = *(const uint4*)(sp);
        uint4 b = *(const uint4*)(sp + 4);
        u16 o[8];
        o[0] = f2b(__builtin_bit_cast(float, a.x));
        o[1] = f2b(__builtin_bit_cast(float, a.y));
        o[2] = f2b(__builtin_bit_cast(float, a.z));
        o[3] = f2b(__builtin_bit_cast(float, a.w));
        o[4] = f2b(__builtin_bit_cast(float, b.x));
        o[5] = f2b(__builtin_bit_cast(float, b.y));
        o[6] = f2b(__builtin_bit_cast(float, b.z));
        o[7] = f2b(__builtin_bit_cast(float, b.w));
        *(uint4*)(d + i) = *(const uint4*)o;
    } else {
        *(uint4*)(d + i) = *(const uint4*)((const u16*)s + i);
    }
}

__global__ void convert_all(const void* x, const void* Wq, const void* bq,
                            const void* Wk, const void* bk, const void* Wv,
                            const void* bv, const void* Wo, const void* bo,
                            u16* __restrict__ xb, u16* __restrict__ Wcat,
                            u16* __restrict__ Wob, u16* __restrict__ bcat,
                            u16* __restrict__ bob, int* __restrict__ flagw)
{
    __shared__ int sflag;
    const int tid = threadIdx.x;
    if (tid == 0) sflag = 0;
    __syncthreads();
    int mybad = 0;
    for (int i = tid; i < 2048; i += 256) {
        float v = b2f(((const u16*)x)[i]);
        if (!(fabsf(v) < 100.f)) mybad = 1;   // fp32 mantissa halves look wild
    }
    if (mybad) atomicOr(&sflag, 1);
    __syncthreads();
    const int f = sflag ? 1 : 0;
    if (blockIdx.x == 0 && tid == 0) *flagw = f;

    long i = ((long)blockIdx.x * 256 + tid) * 8;
    if (i < NX)            { cvt8(x,  xb,           i, f); return; }
    i -= NX;
    if (i < NW)            { cvt8(Wq, Wcat,         i, f); return; }
    i -= NW;
    if (i < NW)            { cvt8(Wk, Wcat + NW,    i, f); return; }
    i -= NW;
    if (i < NW)            { cvt8(Wv, Wcat + 2*NW,  i, f); return; }
    i -= NW;
    if (i < NW)            { cvt8(Wo, Wob,          i, f); return; }
    i -= NW;
    if (i < 512)           { cvt8(bq, bcat,         i, f); return; }
    i -= 512;
    if (i < 512)           { cvt8(bk, bcat + 512,   i, f); return; }
    i -= 512;
    if (i < 512)           { cvt8(bv, bcat + 1024,  i, f); return; }
    i -= 512;
    if (i < 512)           { cvt8(bo, bob,          i, f); }
}

// 256x128-tile GEMM, K=512. Round-16: exact r14/r9 structure (best stable
// measured config; totals 190-195us across three containers).
// r15 post-mortem: __launch_bounds__(512,1) did NOT lift the 128-VGPR
// allocator cap for 8-wave blocks (VGPR_Count stayed 128, scratch WRITE
// stayed ~113MB) - acc[8][4] at 512 threads spills structurally; the
// 256x256 intensity geometry is dead at HIP source level. GEMM
// microstructure exploration closed per pre-commitment.
// Structure: 8 waves 4Mx2N (64x64/wave), BK=64, 3-tile ring (144KB,
// 1 blk/CU), fully unrolled (static LDS indices), ONE barrier per K-tile,
// counted vmcnt(6): tile t+1 landed, t+2's 6 loads stay in flight across
// the barrier; never drain to 0 mid-loop. No XCD swizzle (r13: default
// x-major dispatch already gives per-XCD A reuse; remap blew FETCH 4x).
// out[m,n] = sum_k A[m,k]*Bw[n,k] + bias[n].
// mode 0 (fused QKV, N=1536): seg0->out0 (Q), seg1->out1 (K), seg2->out2
//   (V TRANSPOSED [(b*8+h)*64+d][t]).  mode 1 (O-proj): out0, fp32 if *flagp.
__global__ __launch_bounds__(512, 2)
void gemm256(const u16* __restrict__ A, const u16* __restrict__ Bw,
             const u16* __restrict__ bias, void* __restrict__ out0,
             u16* __restrict__ out1, u16* __restrict__ out2,
             int mode, const int* __restrict__ flagp)
{
    __shared__ __align__(16) u16 AsF[3][256 * 64];   // 96 KB
    __shared__ __align__(16) u16 BsF[3][128 * 64];   // 48 KB (144 KB, 1 blk/CU)

    const int tid  = threadIdx.x;
    const int lane = tid & 63;
    const int wv   = tid >> 6;          // 0..7
    const int col  = lane & 15;
    const int quad = lane >> 4;
    const int wm   = (wv >> 1) * 64;    // 0,64,128,192
    const int wn   = (wv & 1) * 64;     // 0,64
    const int m0   = blockIdx.x * 256;
    const int n0   = blockIdx.y * 128;

    f32x4 acc[4][4] = {};

    // staging: lane l covers row-in-group lr=l>>3, 16B slot lc=l&7;
    // source k-slot XOR-swizzled by row&7 (= lr, groups 8-row-aligned).
    const int lr  = lane >> 3;
    const int lc  = lane & 7;
    const int cbs = lc ^ lr;

    auto STG = [&](int buf, int k0, int half) {
        #pragma unroll
        for (int i = 0; i < 2; i++) {
            const int g = wv * 4 + half * 2 + i;          // 0..31 (256 rows)
            gl_lds(A + (size_t)(m0 + g * 8 + lr) * 512 + k0 + cbs * 8,
                   &AsF[buf][g * 512]);
        }
        const int g2 = wv * 2 + half;                     // 0..15 (128 rows)
        gl_lds(Bw + (size_t)(n0 + g2 * 8 + lr) * 512 + k0 + cbs * 8,
               &BsF[buf][g2 * 512]);
    };

    // prologue: tiles 0,1 staged (12 loads/wave); wait 6 => tile 0 landed
    STG(0, 0, 0);  STG(0, 0, 1);
    STG(1, 64, 0); STG(1, 64, 1);
    asm volatile("s_waitcnt vmcnt(6)" ::: "memory");
    __builtin_amdgcn_s_barrier();
    __builtin_amdgcn_sched_barrier(0);

    #pragma unroll
    for (int t = 0; t < 8; t++) {                 // static after full unroll
        const int p  = t % 3;
        const int q  = (t + 2) % 3;
        const int k2 = (t + 2) * 64;
        bf16x8 fa[2][4], fb[2][4];
        #pragma unroll
        for (int mi = 0; mi < 4; mi++)
            fa[0][mi] = ldsfrag(&AsF[p][(wm + mi * 16 + col) * 64 + ((0 + quad) ^ (col & 7)) * 8]);
        #pragma unroll
        for (int ni = 0; ni < 4; ni++)
            fb[0][ni] = ldsfrag(&BsF[p][(wn + ni * 16 + col) * 64 + ((0 + quad) ^ (col & 7)) * 8]);
        if (t < 6) STG(q, k2, 0);
        #pragma unroll
        for (int mi = 0; mi < 4; mi++)
            fa[1][mi] = ldsfrag(&AsF[p][(wm + mi * 16 + col) * 64 + ((4 + quad) ^ (col & 7)) * 8]);
        #pragma unroll
        for (int ni = 0; ni < 4; ni++)
            fb[1][ni] = ldsfrag(&BsF[p][(wn + ni * 16 + col) * 64 + ((4 + quad) ^ (col & 7)) * 8]);
        if (t < 6) STG(q, k2, 1);
        asm volatile("s_waitcnt lgkmcnt(0)" ::: "memory");
        __builtin_amdgcn_sched_barrier(0);
        __builtin_amdgcn_s_setprio(1);
        #pragma unroll
        for (int kk = 0; kk < 2; kk++)
            #pragma unroll
            for (int mi = 0; mi < 4; mi++)
                #pragma unroll
                for (int ni = 0; ni < 4; ni++)
                    acc[mi][ni] = mfma16(fa[kk][mi], fb[kk][ni], acc[mi][ni]);
        __builtin_amdgcn_s_setprio(0);
        if (t < 6)      asm volatile("s_waitcnt vmcnt(6)" ::: "memory");
        else if (t == 6) asm volatile("s_waitcnt vmcnt(0)" ::: "memory");
        if (t < 7) {
            __builtin_amdgcn_s_barrier();
            __builtin_amdgcn_sched_barrier(0);
        }
    }

    if (mode == 0) {
        #pragma unroll
        for (int ni = 0; ni < 4; ni++) {
            const int gn = n0 + wn + ni * 16 + col;     // 0..1535
            const float bv = b2f(bias[gn]);
            const int seg = gn >> 9;
            #pragma unroll
            for (int mi = 0; mi < 4; mi++) {
                const int gmb = m0 + wm + mi * 16 + quad * 4;
                if (seg < 2) {
                    u16* dst = (seg == 0) ? (u16*)out0 : out1;
                    #pragma unroll
                    for (int r = 0; r < 4; r++)
                        dst[(size_t)(gmb + r) * 512 + (gn & 511)] = f2b(acc[mi][ni][r] + bv);
                } else {
                    const int d = gn & 63, hh = (gn >> 6) & 7;
                    const int bb = gmb >> 13, t = gmb & 8191;
                    u16 pb[4];
                    #pragma unroll
                    for (int r = 0; r < 4; r++) pb[r] = f2b(acc[mi][ni][r] + bv);
                    uint2 pk;
                    pk.x = pb[0] | ((u32)pb[1] << 16);
                    pk.y = pb[2] | ((u32)pb[3] << 16);
                    *(uint2*)&out2[((size_t)(bb * 8 + hh) * 64 + d) * 8192 + t] = pk;
                }
            }
        }
    } else {
        const int outf32 = *flagp;
        #pragma unroll
        for (int ni = 0; ni < 4; ni++) {
            const int gn = n0 + wn + ni * 16 + col;
            const float bv = b2f(bias[gn]);
            #pragma unroll
            for (int mi = 0; mi < 4; mi++) {
                #pragma unroll
                for (int r = 0; r < 4; r++) {
                    const int gm = m0 + wm + mi * 16 + quad * 4 + r;
                    const float v = acc[mi][ni][r] + bv;
                    if (outf32) ((float*)out0)[(size_t)gm * 512 + gn] = v;
                    else        ((u16*)out0)[(size_t)gm * 512 + gn]  = f2b(v);
                }
            }
        }
    }
}

// Local attention, block = (b,h,chunk): 256 queries, 8 waves x 32 queries.
// Round-10 structure kept (measured good): P in registers - Ps LDS
// round-trip eliminated via the key<->k-slot remap kappa(kt,quad,j) =
// (2kt+(j>>2))*16+quad*4+(j&3); PV's B-fragment is the lane's own QK^T
// output, V read as 2x ds_read_b64 per di with the same map. LDS 32KB.
// No max-subtraction (scores O(6), softmax shift-invariant).
__global__ __launch_bounds__(512, 4)
void attn_local(const u16* __restrict__ Qg, const u16* __restrict__ Kg,
                const u16* __restrict__ VTg, u16* __restrict__ Og)
{
    __shared__ __align__(16) u16 Ks[2][64 * 64];   // 16 KB
    __shared__ __align__(16) u16 VTs[2][64 * 64];  // 16 KB (32 KB total)

    const int tid  = threadIdx.x;
    const int lane = tid & 63;
    const int wv   = tid >> 6;          // 0..7
    const int col  = lane & 15;
    const int quad = lane >> 4;

    const int idx = blockIdx.x;
    const int c = idx & 31;
    const int h = (idx >> 5) & 7;
    const int b = idx >> 8;

    const int t0 = c * WW;
    const int wq = wv * 32;             // this wave's 32 queries

    const int sc_lo = (c == 0) ? 4 : 0;                 // kstart >= 0
    const int nsc   = (c == 0 || c == 31) ? 8 : 12;     // kstart < T

    const int ldr = lane >> 3;            // staging row-within-group (0..7)
    const int ldc = lane & 7;

    // Q fragments (B-operand): lane holds Q[t0+wq+qi*16+col][kk*32+quad*8..+8]
    bf16x8 qf[2][2];
    {
        const size_t qbase = ((size_t)(b * TT + t0 + wq + col)) * DD + h * DH + quad * 8;
        #pragma unroll
        for (int qi = 0; qi < 2; qi++)
            #pragma unroll
            for (int kk = 0; kk < 2; kk++)
                qf[qi][kk] = *(const bf16x8*)(Qg + qbase + (size_t)qi * 16 * DD + kk * 32);
    }

    f32x4 o[4][2] = {};                 // O^T accum: [di(d-tile)][qi(q-tile)]
    float lsum[2] = {0.f, 0.f};         // per-lane partial l for q=qi*16+col

    // prefetch first sub-chunk into buf 0 (one K + one VT row-group per wave)
    {
        const int kstart = t0 - WW + sc_lo * 64;
        const int rr = wv * 8 + ldr;
        const int cb = ldc ^ (rr & 7);
        gl_lds(Kg  + ((size_t)(b * TT + kstart + rr)) * DD + h * DH + cb * 8,
               &Ks[0][wv * 512]);
        gl_lds(VTg + ((size_t)((b * HH + h) * DH + rr)) * TT + kstart + cb * 8,
               &VTs[0][wv * 512]);
    }

    for (int it = 0; it < nsc; it++) {
        __syncthreads();   // drains loads for buf it&1; prev readers of other buf done
        if (it + 1 < nsc) {
            const int kstart = t0 - WW + (sc_lo + it + 1) * 64;
            const int buf = (it + 1) & 1;
            const int rr = wv * 8 + ldr;
            const int cb = ldc ^ (rr & 7);
            gl_lds(Kg  + ((size_t)(b * TT + kstart + rr)) * DD + h * DH + cb * 8,
                   &Ks[buf][wv * 512]);
            gl_lds(VTg + ((size_t)((b * HH + h) * DH + rr)) * TT + kstart + cb * 8,
                   &VTs[buf][wv * 512]);
        }
        const u16* ks = &Ks[it & 1][0];
        const u16* vs = &VTs[it & 1][0];

        #pragma unroll
        for (int half = 0; half < 2; half++) {      // half == kt
            uint2 p2[2][2];                          // [nsl][qi] packed bf16 p
            #pragma unroll
            for (int nsl = 0; nsl < 2; nsl++) {
                const int ns = half * 2 + nsl;
                const int row = ns * 16 + col;
                bf16x8 ka0 = ldsfrag(&ks[row * 64 + ((0 + quad) ^ (col & 7)) * 8]);
                bf16x8 ka1 = ldsfrag(&ks[row * 64 + ((4 + quad) ^ (col & 7)) * 8]);
                #pragma unroll
                for (int qi = 0; qi < 2; qi++) {
                    f32x4 sv = (f32x4){0.f, 0.f, 0.f, 0.f};
                    sv = mfma16(ka0, qf[qi][0], sv);
                    sv = mfma16(ka1, qf[qi][1], sv);
                    u16 pb[4];
                    #pragma unroll
                    for (int r = 0; r < 4; r++) {
                        const float p = __expf(sv[r] * 0.125f);
                        pb[r] = f2b(p);
                        lsum[qi] += p;
                    }
                    p2[nsl][qi].x = pb[0] | ((u32)pb[1] << 16);
                    p2[nsl][qi].y = pb[2] | ((u32)pb[3] << 16);
                }
            }
            // PV kt=half. B-fragment is lane-local: element j = p[2kt+(j>>2)][j&3]
            bf16x8 pf[2];
            #pragma unroll
            for (int qi = 0; qi < 2; qi++) {
                uint4 w;
                w.x = p2[0][qi].x; w.y = p2[0][qi].y;
                w.z = p2[1][qi].x; w.w = p2[1][qi].y;
                pf[qi] = __builtin_bit_cast(bf16x8, w);
            }
            // V fragment: element j = VT[d][kappa] -> two b64 chunks per di
            const int glo = (half * 4 +     (quad >> 1)) ^ (col & 7);
            const int ghi = (half * 4 + 2 + (quad >> 1)) ^ (col & 7);
            const int hb  = (quad & 1) * 8;              // byte offset in granule
            #pragma unroll
            for (int di = 0; di < 4; di++) {
                const char* rowp = (const char*)&vs[(di * 16 + col) * 64];
                uint2 lo = *(const uint2*)(rowp + glo * 16 + hb);
                uint2 hi = *(const uint2*)(rowp + ghi * 16 + hb);
                uint4 w4;
                w4.x = lo.x; w4.y = lo.y; w4.z = hi.x; w4.w = hi.y;
                bf16x8 va = __builtin_bit_cast(bf16x8, w4);
                #pragma unroll
                for (int qi = 0; qi < 2; qi++)
                    o[di][qi] = mfma16(va, pf[qi], o[di][qi]);
            }
        }
    }

    // final l reduction over quads (lanes col,col+16,col+32,col+48 share q)
    #pragma unroll
    for (int qi = 0; qi < 2; qi++) {
        float l = lsum[qi];
        l += __shfl_xor(l, 16);
        l += __shfl_xor(l, 32);
        lsum[qi] = 1.0f / l;
    }

    // store O^T: element (di,qi,r): d = di*16+quad*4+r, q = qi*16+col
    #pragma unroll
    for (int qi = 0; qi < 2; qi++) {
        const size_t ob = ((size_t)(b * TT + t0 + wq + qi * 16 + col)) * DD + h * DH + quad * 4;
        #pragma unroll
        for (int di = 0; di < 4; di++) {
            u16 pb[4];
            #pragma unroll
            for (int r = 0; r < 4; r++) pb[r] = f2b(o[di][qi][r] * lsum[qi]);
            uint2 pk;
            pk.x = pb[0] | ((u32)pb[1] << 16);
            pk.y = pb[2] | ((u32)pb[3] << 16);
            *(uint2*)&Og[ob + di * 16] = pk;
        }
    }
}

extern "C" void kernel_launch(void* const* d_in, const int* in_sizes, int n_in,
                              void* d_out, int out_size, void* d_ws, size_t ws_size,
                              hipStream_t stream)
{
    u16* ws   = (u16*)d_ws;
    u16* xb   = ws;                       // NX
    u16* Wcat = xb + NX;                  // 3*NW  (Wq,Wk,Wv rows concatenated)
    u16* Wob  = Wcat + 3 * NW;            // NW
    u16* bcat = Wob + NW;                 // 1536
    u16* bob  = bcat + 1536;              // 512
    u16* qws  = bob + 512;                // NX   Q  [b*T+t][h*64+d]
    u16* kws  = qws + NX;                 // NX   K  same
    u16* vtws = kws + NX;                 // NX   V^T [(b*8+h)*64+d][t]
    u16* aws  = vtws + NX;                // NX   attn out [b*T+t][h*64+d]
    int* flag = (int*)(aws + NX);

    // 9439232 elements / 8 per thread / 256 per block = 4609 blocks
    convert_all<<<4609, 256, 0, stream>>>(
        d_in[0], d_in[1], d_in[2], d_in[3], d_in[4], d_in[5], d_in[6], d_in[7], d_in[8],
        xb, Wcat, Wob, bcat, bob, flag);

    // fused QKV projection: N = 1536, 256x128 tiles -> 64x12 = 768 blocks
    gemm256<<<dim3(64, 12), 512, 0, stream>>>(xb, Wcat, bcat, qws, kws, vtws, 0, flag);
    // local attention: 512 blocks x 512 threads
    attn_local<<<dim3(BB * HH * 32), 512, 0, stream>>>(qws, kws, vtws, aws);
    // output projection: 64x4 = 256 blocks = 1 exact round
    gemm256<<<dim3(64, 4), 512, 0, stream>>>(aws, Wob, bob, d_out, nullptr, nullptr, 1, flag);
}